// Round 3
// baseline (245.734 us; speedup 1.0000x reference)
//
#include <hip/hip_runtime.h>

typedef unsigned short ushort_t;
typedef unsigned int u32;
typedef short bf16x8 __attribute__((ext_vector_type(8)));
typedef float f32x4 __attribute__((ext_vector_type(4)));
typedef u32 u32x4 __attribute__((ext_vector_type(4)));

__device__ __forceinline__ float bf2f(ushort_t u) {
    u32 x = ((u32)u) << 16; float f; __builtin_memcpy(&f, &x, 4); return f;
}
__device__ __forceinline__ ushort_t f2bf(float f) {
    u32 x; __builtin_memcpy(&x, &f, 4);
    x = x + 0x7fffu + ((x >> 16) & 1u);
    return (ushort_t)(x >> 16);
}

#define GLDS(gsrc, ldst) __builtin_amdgcn_global_load_lds( \
    (const __attribute__((address_space(1))) u32*)(gsrc), \
    (__attribute__((address_space(3))) u32*)(ldst), 16, 0, 0)

#define NBB 384                       /* base rows per block */
#define UROWS 392                     /* NBB + 8 halo */
#define USTRB 208                     /* bytes per U row (96 bf16 + pad) */
#define UB_BYTES (UROWS * USTRB)      /* 81536 */
#define SLAB_B 36864                  /* per-tap weight slab, both phases */
#define LDS_TOTAL (UB_BYTES + 2 * SLAB_B) /* 155264 <= 160K */

// ---------- prep 1: fold unpool+mask -> Wplain f32 [stage][o][cc][k] ----------
__global__ void prep_fold(const float* __restrict__ w0, const float* __restrict__ m0,
                          const float* __restrict__ w1, const float* __restrict__ m1,
                          float* __restrict__ Wplain)
{
    int idx = blockIdx.x * 256 + threadIdx.x;
    if (idx >= 2 * 96 * 96 * 15) return;
    int k = idx % 15;
    int cc = (idx / 15) % 96;
    int o = (idx / (15 * 96)) % 96;
    int st = idx / (15 * 96 * 96);
    const float* w = st ? w1 : w0;
    const float* mk = st ? m1 : m0;
    int cpj = st ? 8 : 16;
    int i = cc / cpj, c = cc % cpj;
    float s = 0.f;
#pragma unroll
    for (int d = 0; d < 2; ++d) {
        int f = (2 * i + d) * cpj + c;
        s += w[(o * 192 + f) * 15 + k] * mk[(o * 192 + f) * 15 + k];
    }
    Wplain[idx] = s;
}

// ---------- prep 2: polyphase weights into MFMA A-frag order ----------
// Wp layout: [(j*2+p)*18 + cb*6 + m2]*512 + lane*8 + e
__global__ void prep_wfrag(const float* __restrict__ Wplain,
                           ushort_t* __restrict__ Wp0, ushort_t* __restrict__ Wp1)
{
    int idx = blockIdx.x * 256 + threadIdx.x;
    if (idx >= 331776) return;                // 2st x 2p x 9j x 96o x 96cc
    int cc = idx % 96; int t = idx / 96;
    int o = t % 96; t /= 96;
    int j = t % 9; t /= 9;
    int p = t % 2; int st = t / 2;
    const float* WP = Wplain + (size_t)st * 96 * 96 * 15;
    int kk[4]; float cf[4];
    if (p == 0) { kk[0]=2*j;   cf[0]=0.75f; kk[1]=2*j-2; cf[1]=0.25f;
                  kk[2]=2*j+1; cf[2]=0.25f; kk[3]=2*j-1; cf[3]=0.75f; }
    else        { kk[0]=2*j;   cf[0]=0.25f; kk[1]=2*j-2; cf[1]=0.75f;
                  kk[2]=2*j-1; cf[2]=0.75f; kk[3]=2*j-3; cf[3]=0.25f; }
    float s = 0.f;
#pragma unroll
    for (int q = 0; q < 4; ++q) {
        int k = kk[q];
        if (k >= 0 && k < 15) s += cf[q] * WP[((size_t)o * 96 + cc) * 15 + k];
    }
    int lane = (o & 15) | (((cc >> 3) & 3) << 4);
    int pos = ((j * 2 + p) * 18 + (cc >> 5) * 6 + (o >> 4)) * 512 + lane * 8 + (cc & 7);
    (st ? Wp1 : Wp0)[pos] = f2bf(s);
}

// ---------- prep 3: ADD[b][o] for both stages ----------
__global__ void prep_add(const float* __restrict__ offw0, const float* __restrict__ offb0,
                         const float* __restrict__ omask0, const float* __restrict__ convb0,
                         const float* __restrict__ off0,
                         const float* __restrict__ offw1, const float* __restrict__ offb1,
                         const float* __restrict__ omask1, const float* __restrict__ convb1,
                         const float* __restrict__ off1,
                         float* __restrict__ ADD0, float* __restrict__ ADD1)
{
    int a = blockIdx.x * 256 + threadIdx.x;
    if (a >= 12288) return;
    int st = a / 6144; int a2 = a % 6144;
    int o = a2 % 96, b = a2 / 96;
    const float* ow = st ? offw1 : offw0;
    const float* ob = st ? offb1 : offb0;
    const float* om = st ? omask1 : omask0;
    const float* cb = st ? convb1 : convb0;
    const float* of = st ? off1 : off0;
    int J = st ? 72 : 36;
    float s = 0.f;
    for (int j2 = 0; j2 < J; ++j2) s += ow[o * J + j2] * om[o * J + j2] * of[b * J + j2];
    (st ? ADD1 : ADD0)[b * 96 + o] = cb[o] + (s + ob[o]) * 0.01f;
}

// ---------- prep 4: boundary corrections CF/CB directly (fused G + prefix) ----
template<int BF16SRC>
__global__ void prep_bnd(const float* __restrict__ WP, const float* __restrict__ srcF,
                         const ushort_t* __restrict__ srcB, float* __restrict__ CF,
                         float* __restrict__ CB, int T)
{
    int idx = blockIdx.x * 256 + threadIdx.x;
    if (idx >= 6144) return;
    int o = idx % 96, b = idx / 96;
    const float* wrow = WP + (size_t)o * 96 * 15;
    float Ga[15], Gb[15];
#pragma unroll
    for (int k = 0; k < 15; ++k) { Ga[k] = 0.f; Gb[k] = 0.f; }
    for (int cc = 0; cc < 96; ++cc) {
        float x0, x1;
        if (BF16SRC) {
            x0 = bf2f(srcB[(size_t)b * T * 96 + cc]);
            x1 = bf2f(srcB[((size_t)b * T + (T - 1)) * 96 + cc]);
        } else {
            x0 = bf2f(f2bf(srcF[(size_t)b * T * 96 + cc]));
            x1 = bf2f(f2bf(srcF[((size_t)b * T + (T - 1)) * 96 + cc]));
        }
        const float* wcc = wrow + cc * 15;
#pragma unroll
        for (int k = 0; k < 15; ++k) {
            float w = wcc[k];
            Ga[k] += w * x0; Gb[k] += w * x1;
        }
    }
#pragma unroll
    for (int t = 0; t < 7; ++t) {
        float s0 = 0.f, s1 = 0.f;
#pragma unroll
        for (int k = 0; k < 15; ++k) { if (k <= 6 - t) s0 += Ga[k]; if (k >= 14 - t) s1 += Gb[k]; }
        CF[(b * 7 + t) * 96 + o] = s0;
        CB[(b * 7 + t) * 96 + o] = s1;
    }
}

// ---------- fused polyphase conv: Rm=6 x Rn=6 per wave, 8 waves, NBB=384 ------
template<int STAGE>
__launch_bounds__(512, 2)
__global__ void conv_poly(const float* __restrict__ Xf, const ushort_t* __restrict__ Hbf,
                          const ushort_t* __restrict__ Wp, const float* __restrict__ ADD,
                          const float* __restrict__ CF, const float* __restrict__ CB,
                          ushort_t* __restrict__ Hout, float* __restrict__ Fout, int T)
{
    extern __shared__ char smem[];
    char* Ub = smem;
    char* wlds = smem + UB_BYTES;

    const int tid = threadIdx.x;
    const int lane = tid & 63;
    const int wid = tid >> 6;
    const int b = blockIdx.y;
    const int tg = blockIdx.x;
    const int phase = wid & 1;
    const int nq = wid >> 1;          // 0..3, 96 base rows each
    const int rb0 = tg * NBB - 4;

    const char* wsrc = (const char*)Wp;
    if (wid < 4)
        for (int i = wid; i < 36; i += 4)
            GLDS(wsrc + i * 1024 + lane * 16, wlds + i * 1024);

    // stage U at base rate, clamped rows, (r&8)<<1 XOR swizzle on 16B granules
    if (STAGE == 0) {
        const float* xb = Xf + (size_t)b * T * 96;
        for (int idx = tid; idx < UROWS * 12; idx += 512) {
            int r = idx / 12, q = idx - r * 12;
            int rg = rb0 + r; rg = rg < 0 ? 0 : (rg > T - 1 ? T - 1 : rg);
            const float* src = xb + (size_t)rg * 96 + q * 8;
            float4 a = *(const float4*)src;
            float4 c2 = *(const float4*)(src + 4);
            u32x4 v;
            v[0] = (u32)f2bf(a.x) | ((u32)f2bf(a.y) << 16);
            v[1] = (u32)f2bf(a.z) | ((u32)f2bf(a.w) << 16);
            v[2] = (u32)f2bf(c2.x) | ((u32)f2bf(c2.y) << 16);
            v[3] = (u32)f2bf(c2.z) | ((u32)f2bf(c2.w) << 16);
            int off = r * USTRB + q * 16; off ^= (r & 8) << 1;
            *(u32x4*)(Ub + off) = v;
        }
    } else {
        const ushort_t* xb = Hbf + (size_t)b * T * 96;
        for (int idx = tid; idx < UROWS * 12; idx += 512) {
            int r = idx / 12, q = idx - r * 12;
            int rg = rb0 + r; rg = rg < 0 ? 0 : (rg > T - 1 ? T - 1 : rg);
            u32x4 v = *(const u32x4*)(xb + (size_t)rg * 96 + q * 8);
            int off = r * USTRB + q * 16; off ^= (r & 8) << 1;
            *(u32x4*)(Ub + off) = v;
        }
    }
    __syncthreads();   // slab0 resident (vmcnt(0) implied), U visible

    f32x4 acc[6][6];
#pragma unroll
    for (int m2 = 0; m2 < 6; ++m2)
#pragma unroll
        for (int n = 0; n < 6; ++n) acc[m2][n] = (f32x4){0.f, 0.f, 0.f, 0.f};

    const int rowbase = 96 * nq + (lane & 15);
    const int og16 = (lane >> 4) * 16;

    for (int j = 0; j < 9; ++j) {
        if (wid < 4) asm volatile("s_waitcnt vmcnt(0)" ::: "memory");
        __builtin_amdgcn_s_barrier();
        if (j + 1 < 9 && wid < 4) {   // prefetch next slab into other buffer
            const char* src = wsrc + (size_t)(j + 1) * SLAB_B;
            char* dst2 = wlds + ((j + 1) & 1) * SLAB_B;
            for (int i = wid; i < 36; i += 4)
                GLDS(src + i * 1024 + lane * 16, dst2 + i * 1024);
        }
        const ushort_t* wb = (const ushort_t*)(wlds + (j & 1) * SLAB_B) + phase * 9216;
#pragma unroll
        for (int cb = 0; cb < 3; ++cb) {
            bf16x8 bfr[6];
#pragma unroll
            for (int n = 0; n < 6; ++n) {
                int row = rowbase + n * 16 + j;
                int off = row * USTRB + cb * 64 + og16; off ^= (row & 8) << 1;
                bfr[n] = *(const bf16x8*)(Ub + off);
            }
            bf16x8 afr[6];
#pragma unroll
            for (int m2 = 0; m2 < 6; ++m2)
                afr[m2] = *(const bf16x8*)(wb + (cb * 6 + m2) * 512 + lane * 8);
            __builtin_amdgcn_s_setprio(1);
#pragma unroll
            for (int m2 = 0; m2 < 6; ++m2)
#pragma unroll
                for (int n = 0; n < 6; ++n)
                    acc[m2][n] = __builtin_amdgcn_mfma_f32_16x16x32_bf16(afr[m2], bfr[n], acc[m2][n], 0, 0, 0);
            __builtin_amdgcn_s_setprio(0);
        }
    }

    // epilogue
    const int T2 = 2 * T;
    const int og = (lane >> 4) * 4;
#pragma unroll
    for (int m2 = 0; m2 < 6; ++m2) {
        int o0 = m2 * 16 + og;
        float addv[4];
#pragma unroll
        for (int rr = 0; rr < 4; ++rr) addv[rr] = ADD[b * 96 + o0 + rr];
#pragma unroll
        for (int n = 0; n < 6; ++n) {
            int mg = tg * NBB + rowbase + n * 16;
            if (mg >= T) continue;
            int t = 2 * mg + phase;
            float v4[4];
#pragma unroll
            for (int rr = 0; rr < 4; ++rr) {
                float v = acc[m2][n][rr] + addv[rr];
                if (t < 7)       v -= CF[(b * 7 + t) * 96 + o0 + rr];
                if (t >= T2 - 7) v -= CB[(b * 7 + (t - (T2 - 7))) * 96 + o0 + rr];
                if (STAGE == 0)  v = v > 0.f ? v : 0.2f * v;
                v4[rr] = v;
            }
            if (STAGE == 0) {
                uint2 st;
                st.x = (u32)f2bf(v4[0]) | ((u32)f2bf(v4[1]) << 16);
                st.y = (u32)f2bf(v4[2]) | ((u32)f2bf(v4[3]) << 16);
                *(uint2*)(Hout + ((size_t)b * T2 + t) * 96 + o0) = st;
            } else {
                if (t < T2 - 1) {
#pragma unroll
                    for (int rr = 0; rr < 4; ++rr)
                        Fout[((size_t)(b * 96 + o0 + rr)) * (T2 - 1) + t] = v4[rr];
                }
            }
        }
    }
}

extern "C" void kernel_launch(void* const* d_in, const int* in_sizes, int n_in,
                              void* d_out, int out_size, void* d_ws, size_t ws_size,
                              hipStream_t stream)
{
    const float* x       = (const float*)d_in[0];
    const float* offset0 = (const float*)d_in[1];
    const float* offset1 = (const float*)d_in[2];
    const float* conv_w0 = (const float*)d_in[5];
    const float* conv_b0 = (const float*)d_in[6];
    const float* conv_w1 = (const float*)d_in[7];
    const float* conv_b1 = (const float*)d_in[8];
    const float* off_w0  = (const float*)d_in[9];
    const float* off_b0  = (const float*)d_in[10];
    const float* off_w1  = (const float*)d_in[11];
    const float* off_b1  = (const float*)d_in[12];
    const float* cmask0  = (const float*)d_in[13];
    const float* cmask1  = (const float*)d_in[14];
    const float* omask0  = (const float*)d_in[15];
    const float* omask1  = (const float*)d_in[16];

    char* ws = (char*)d_ws;
    float*    Wplain = (float*)(ws);                  // 1,105,920
    ushort_t* Wp0    = (ushort_t*)(ws + 1105920);     // 331,776
    ushort_t* Wp1    = (ushort_t*)(ws + 1437696);     // 331,776
    float*    ADD0   = (float*)(ws + 1769472);        // 24,576
    float*    ADD1   = (float*)(ws + 1794048);        // 24,576
    float*    CF0    = (float*)(ws + 1818624);        // 172,032
    float*    CB0    = (float*)(ws + 1990656);        // 172,032
    float*    CF1    = (float*)(ws + 2162688);        // 172,032
    float*    CB1    = (float*)(ws + 2334720);        // 172,032
    ushort_t* H1     = (ushort_t*)(ws + 2506752);     // 25,165,824
    float* out = (float*)d_out;

    prep_fold<<<1080, 256, 0, stream>>>(conv_w0, cmask0, conv_w1, cmask1, Wplain);
    prep_wfrag<<<1296, 256, 0, stream>>>(Wplain, Wp0, Wp1);
    prep_add<<<48, 256, 0, stream>>>(off_w0, off_b0, omask0, conv_b0, offset0,
                                     off_w1, off_b1, omask1, conv_b1, offset1,
                                     ADD0, ADD1);
    prep_bnd<0><<<24, 256, 0, stream>>>(Wplain, x, nullptr, CF0, CB0, 1024);

    (void)hipFuncSetAttribute(reinterpret_cast<const void*>(&conv_poly<0>),
                              hipFuncAttributeMaxDynamicSharedMemorySize, LDS_TOTAL);
    (void)hipFuncSetAttribute(reinterpret_cast<const void*>(&conv_poly<1>),
                              hipFuncAttributeMaxDynamicSharedMemorySize, LDS_TOTAL);

    conv_poly<0><<<dim3(3, 64), 512, LDS_TOTAL, stream>>>(x, nullptr, Wp0, ADD0, CF0, CB0,
                                                          H1, nullptr, 1024);
    prep_bnd<1><<<24, 256, 0, stream>>>(Wplain + (size_t)96 * 96 * 15, nullptr, H1, CF1, CB1, 2048);
    conv_poly<1><<<dim3(6, 64), 512, LDS_TOTAL, stream>>>(nullptr, H1, Wp1, ADD1, CF1, CB1,
                                                          nullptr, out, 2048);
}

// Round 4
// 216.539 us; speedup vs baseline: 1.1348x; 1.1348x over previous
//
#include <hip/hip_runtime.h>

typedef unsigned short ushort_t;
typedef unsigned int u32;
typedef short bf16x8 __attribute__((ext_vector_type(8)));
typedef float f32x4 __attribute__((ext_vector_type(4)));
typedef u32 u32x4 __attribute__((ext_vector_type(4)));

__device__ __forceinline__ float bf2f(ushort_t u) {
    u32 x = ((u32)u) << 16; float f; __builtin_memcpy(&f, &x, 4); return f;
}
__device__ __forceinline__ ushort_t f2bf(float f) {
    u32 x; __builtin_memcpy(&x, &f, 4);
    x = x + 0x7fffu + ((x >> 16) & 1u);
    return (ushort_t)(x >> 16);
}

#define GLDS(gsrc, ldst) __builtin_amdgcn_global_load_lds( \
    (const __attribute__((address_space(1))) u32*)(gsrc), \
    (__attribute__((address_space(3))) u32*)(ldst), 16, 0, 0)

#define NBB 192                       /* base rows per block */
#define UROWS 200                     /* NBB + 8 halo */
#define USTRB 208                     /* bytes per U row (96 bf16 + pad) */
#define UB_BYTES (UROWS * USTRB)      /* 41600 */
#define WHALF_B 18432                 /* per-tap, per o-half weight slab */
#define LDS_TOTAL (UB_BYTES + 2 * WHALF_B) /* 78464 -> 2 blocks/CU */

// ---------- prepA: fold unpool+mask -> Wplain [st][cc][k][o]  +  ADD tables ----
__global__ void prepA(const float* __restrict__ w0, const float* __restrict__ m0,
                      const float* __restrict__ w1, const float* __restrict__ m1,
                      const float* __restrict__ offw0, const float* __restrict__ offb0,
                      const float* __restrict__ omask0, const float* __restrict__ convb0,
                      const float* __restrict__ off0,
                      const float* __restrict__ offw1, const float* __restrict__ offb1,
                      const float* __restrict__ omask1, const float* __restrict__ convb1,
                      const float* __restrict__ off1,
                      float* __restrict__ Wplain, float* __restrict__ ADD0,
                      float* __restrict__ ADD1)
{
    int idx = blockIdx.x * 256 + threadIdx.x;
    if (idx < 276480) {                       // o fastest -> coalesced writes
        int o = idx % 96;
        int k = (idx / 96) % 15;
        int cc = (idx / 1440) % 96;
        int st = idx / 138240;
        const float* w = st ? w1 : w0;
        const float* mk = st ? m1 : m0;
        int cpj = st ? 8 : 16;
        int i = cc / cpj, c = cc % cpj;
        float s = 0.f;
#pragma unroll
        for (int d = 0; d < 2; ++d) {
            int f = (2 * i + d) * cpj + c;
            s += w[(o * 192 + f) * 15 + k] * mk[(o * 192 + f) * 15 + k];
        }
        Wplain[st * 138240 + (cc * 15 + k) * 96 + o] = s;
    } else if (idx < 276480 + 12288) {
        int a = idx - 276480;
        int st = a / 6144; int a2 = a % 6144;
        int o = a2 % 96, b = a2 / 96;
        const float* ow = st ? offw1 : offw0;
        const float* ob = st ? offb1 : offb0;
        const float* om = st ? omask1 : omask0;
        const float* cb = st ? convb1 : convb0;
        const float* of = st ? off1 : off0;
        int J = st ? 72 : 36;
        float s = 0.f;
        for (int j2 = 0; j2 < J; ++j2) s += ow[o * J + j2] * om[o * J + j2] * of[b * J + j2];
        (st ? ADD1 : ADD0)[b * 96 + o] = cb[o] + (s + ob[o]) * 0.01f;
    }
}

// ---------- boundary-correction helper (Wplain layout [cc][k][o]) ----------
template<int BF16SRC>
__device__ __forceinline__ void bnd_compute(const float* __restrict__ WP,
                                            const float* __restrict__ srcF,
                                            const ushort_t* __restrict__ srcB,
                                            float* __restrict__ CF, float* __restrict__ CB,
                                            int T, int b, int o)
{
    float Ga[15], Gb[15];
#pragma unroll
    for (int k = 0; k < 15; ++k) { Ga[k] = 0.f; Gb[k] = 0.f; }
    for (int cc = 0; cc < 96; ++cc) {
        float x0, x1;
        if (BF16SRC) {
            x0 = bf2f(srcB[(size_t)b * T * 96 + cc]);
            x1 = bf2f(srcB[((size_t)b * T + (T - 1)) * 96 + cc]);
        } else {
            x0 = bf2f(f2bf(srcF[(size_t)b * T * 96 + cc]));
            x1 = bf2f(f2bf(srcF[((size_t)b * T + (T - 1)) * 96 + cc]));
        }
        const float* wb2 = WP + cc * 15 * 96 + o;
#pragma unroll
        for (int k = 0; k < 15; ++k) {
            float w = wb2[k * 96];
            Ga[k] += w * x0; Gb[k] += w * x1;
        }
    }
#pragma unroll
    for (int t = 0; t < 7; ++t) {
        float s0 = 0.f, s1 = 0.f;
#pragma unroll
        for (int k = 0; k < 15; ++k) { if (k <= 6 - t) s0 += Ga[k]; if (k >= 14 - t) s1 += Gb[k]; }
        CF[(b * 7 + t) * 96 + o] = s0;
        CB[(b * 7 + t) * 96 + o] = s1;
    }
}

// ---------- prepB: polyphase A-frag weights (o-half-split layout) + stage0 bnd --
// Wp: [(j*2+mh)*9216 + (p*9 + cb*3 + m2')*512 + lane*8 + e] ushorts
__global__ void prepB(const float* __restrict__ Wplain, const float* __restrict__ x,
                      ushort_t* __restrict__ Wp0, ushort_t* __restrict__ Wp1,
                      float* __restrict__ CF0, float* __restrict__ CB0)
{
    int idx = blockIdx.x * 256 + threadIdx.x;
    if (idx < 331776) {                       // 2st x 2p x 9j x 96o x 96cc
        int cc = idx % 96; int t = idx / 96;
        int o = t % 96; t /= 96;
        int j = t % 9; t /= 9;
        int p = t % 2; int st = t / 2;
        const float* WP = Wplain + (size_t)st * 138240;
        int kk[4]; float cf[4];
        if (p == 0) { kk[0]=2*j;   cf[0]=0.75f; kk[1]=2*j-2; cf[1]=0.25f;
                      kk[2]=2*j+1; cf[2]=0.25f; kk[3]=2*j-1; cf[3]=0.75f; }
        else        { kk[0]=2*j;   cf[0]=0.25f; kk[1]=2*j-2; cf[1]=0.75f;
                      kk[2]=2*j-1; cf[2]=0.75f; kk[3]=2*j-3; cf[3]=0.25f; }
        float s = 0.f;
#pragma unroll
        for (int q = 0; q < 4; ++q) {
            int k = kk[q];
            if (k >= 0 && k < 15) s += cf[q] * WP[(cc * 15 + k) * 96 + o];
        }
        int lane = (o & 15) | (((cc >> 3) & 3) << 4);
        int mh = (o >> 4) / 3, m2p = (o >> 4) % 3;
        int pos = (j * 2 + mh) * 9216 + (p * 9 + (cc >> 5) * 3 + m2p) * 512 + lane * 8 + (cc & 7);
        (st ? Wp1 : Wp0)[pos] = f2bf(s);
    } else if (idx < 331776 + 6144) {
        int a = idx - 331776;
        int o = a % 96, b = a / 96;
        bnd_compute<0>(Wplain, x, nullptr, CF0, CB0, 1024, b, o);
    }
}

__global__ void prep_bnd1(const float* __restrict__ WP, const ushort_t* __restrict__ H1,
                          float* __restrict__ CF, float* __restrict__ CB)
{
    int idx = blockIdx.x * 64 + threadIdx.x;
    if (idx >= 6144) return;
    int o = idx % 96, b = idx / 96;
    bnd_compute<1>(WP, nullptr, H1, CF, CB, 2048, b, o);
}

// ---------- fused polyphase conv; block = o-half x 192 base rows, 4 waves ------
template<int STAGE>
__launch_bounds__(256, 2)
__global__ void conv_poly(const float* __restrict__ Xf, const ushort_t* __restrict__ Hbf,
                          const ushort_t* __restrict__ Wp, const float* __restrict__ ADD,
                          const float* __restrict__ CF, const float* __restrict__ CB,
                          ushort_t* __restrict__ Hout, float* __restrict__ Fout, int T)
{
    extern __shared__ char smem[];
    char* Ub = smem;
    char* wlds = smem + UB_BYTES;

    const int tid = threadIdx.x;
    const int lane = tid & 63;
    const int wid = tid >> 6;         // 0..3
    const int b = blockIdx.y;
    const int tg = blockIdx.x;
    const int mh = blockIdx.z;        // output-channel half (0: o<48, 1: o>=48)
    const int phase = wid & 1;
    const int nq = wid >> 1;          // 0..1, 96 base rows each
    const int rb0 = tg * NBB - 4;

    const char* wsrc = (const char*)Wp;
    // issue slab j=0 (overlaps U staging)
    for (int i = wid; i < 18; i += 4)
        GLDS(wsrc + (size_t)mh * WHALF_B + i * 1024 + lane * 16, wlds + i * 1024);

    // stage U at base rate, clamped rows, (r&8)<<1 XOR swizzle on 16B granules
    if (STAGE == 0) {
        const float* xb = Xf + (size_t)b * T * 96;
        for (int idx = tid; idx < UROWS * 12; idx += 256) {
            int r = idx / 12, q = idx - r * 12;
            int rg = rb0 + r; rg = rg < 0 ? 0 : (rg > T - 1 ? T - 1 : rg);
            const float* src = xb + (size_t)rg * 96 + q * 8;
            float4 a = *(const float4*)src;
            float4 c2 = *(const float4*)(src + 4);
            u32x4 v;
            v[0] = (u32)f2bf(a.x) | ((u32)f2bf(a.y) << 16);
            v[1] = (u32)f2bf(a.z) | ((u32)f2bf(a.w) << 16);
            v[2] = (u32)f2bf(c2.x) | ((u32)f2bf(c2.y) << 16);
            v[3] = (u32)f2bf(c2.z) | ((u32)f2bf(c2.w) << 16);
            int off = r * USTRB + q * 16; off ^= (r & 8) << 1;
            *(u32x4*)(Ub + off) = v;
        }
    } else {
        const ushort_t* xb = Hbf + (size_t)b * T * 96;
        for (int idx = tid; idx < UROWS * 12; idx += 256) {
            int r = idx / 12, q = idx - r * 12;
            int rg = rb0 + r; rg = rg < 0 ? 0 : (rg > T - 1 ? T - 1 : rg);
            u32x4 v = *(const u32x4*)(xb + (size_t)rg * 96 + q * 8);
            int off = r * USTRB + q * 16; off ^= (r & 8) << 1;
            *(u32x4*)(Ub + off) = v;
        }
    }
    __syncthreads();   // slab0 resident, U visible

    f32x4 acc[3][6];
#pragma unroll
    for (int m = 0; m < 3; ++m)
#pragma unroll
        for (int n = 0; n < 6; ++n) acc[m][n] = (f32x4){0.f, 0.f, 0.f, 0.f};

    const int rowbase = 96 * nq + (lane & 15);
    const int og16 = (lane >> 4) * 16;

    for (int j = 0; j < 9; ++j) {
        if (j < 8) {   // prefetch next slab into other buffer
            const char* src = wsrc + (size_t)((j + 1) * 2 + mh) * WHALF_B;
            char* dst2 = wlds + ((j + 1) & 1) * WHALF_B;
            for (int i = wid; i < 18; i += 4)
                GLDS(src + i * 1024 + lane * 16, dst2 + i * 1024);
        }
        const ushort_t* wb = (const ushort_t*)(wlds + (j & 1) * WHALF_B) + phase * 4608;
#pragma unroll
        for (int cb = 0; cb < 3; ++cb) {
            bf16x8 bfr[6];
#pragma unroll
            for (int n = 0; n < 6; ++n) {
                int row = rowbase + n * 16 + j;
                int off = row * USTRB + cb * 64 + og16; off ^= (row & 8) << 1;
                bfr[n] = *(const bf16x8*)(Ub + off);
            }
            bf16x8 afr[3];
#pragma unroll
            for (int m = 0; m < 3; ++m)
                afr[m] = *(const bf16x8*)(wb + (cb * 3 + m) * 512 + lane * 8);
            __builtin_amdgcn_s_setprio(1);
#pragma unroll
            for (int m = 0; m < 3; ++m)
#pragma unroll
                for (int n = 0; n < 6; ++n)
                    acc[m][n] = __builtin_amdgcn_mfma_f32_16x16x32_bf16(afr[m], bfr[n], acc[m][n], 0, 0, 0);
            __builtin_amdgcn_s_setprio(0);
        }
        asm volatile("s_waitcnt vmcnt(0)" ::: "memory");
        __builtin_amdgcn_s_barrier();
        __builtin_amdgcn_sched_barrier(0);
    }

    // ---------------- epilogue: LDS transpose -> coalesced stores --------------
    const int T2 = 2 * T;
    const int t0 = tg * 2 * NBB;          // block's output t-range base (384 wide)
    const int og4 = (lane >> 4) * 4;

    if (STAGE == 0) {
        // deposit all 48 ch x 384 t as bf16 rows [t][48ch] (stride 104 B)
        ushort_t* L0 = (ushort_t*)Ub;
#pragma unroll
        for (int m = 0; m < 3; ++m) {
            int obase = mh * 48 + m * 16 + og4;
            float addv[4];
#pragma unroll
            for (int rr = 0; rr < 4; ++rr) addv[rr] = ADD[b * 96 + obase + rr];
#pragma unroll
            for (int n = 0; n < 6; ++n) {
                int tl = 2 * (rowbase + 16 * n) + phase;   // 0..383
                int tgl = t0 + tl;
                ushort_t pk[4];
#pragma unroll
                for (int rr = 0; rr < 4; ++rr) {
                    float v = acc[m][n][rr] + addv[rr];
                    if (tgl < 7)                  v -= CF[(b * 7 + tgl) * 96 + obase + rr];
                    if (tgl >= T2 - 7 && tgl < T2) v -= CB[(b * 7 + tgl - (T2 - 7)) * 96 + obase + rr];
                    v = v > 0.f ? v : 0.2f * v;
                    pk[rr] = f2bf(v);
                }
                uint2 w2;
                w2.x = (u32)pk[0] | ((u32)pk[1] << 16);
                w2.y = (u32)pk[2] | ((u32)pk[3] << 16);
                *(uint2*)((char*)L0 + tl * 104 + (m * 16 + og4) * 2) = w2;
            }
        }
        __syncthreads();
        // store contiguous 96B half-rows of H1 [b][t][96]
        for (int g = tid; g < 384 * 6; g += 256) {
            int row = g / 6, col = g % 6;
            int t = t0 + row;
            if (t < T2) {
                u32x4 v = *(const u32x4*)((char*)L0 + row * 104 + col * 16);
                *(u32x4*)((char*)Hout + ((size_t)(b * T2 + t) * 96 + mh * 48) * 2 + col * 16) = v;
            }
        }
    } else {
        const int TO = T2 - 1;   // 4095
        float* L1 = (float*)Ub;  // per-chunk [16 o][388 f32]
#pragma unroll
        for (int m = 0; m < 3; ++m) {
            int obase = mh * 48 + m * 16 + og4;
            float addv[4];
#pragma unroll
            for (int rr = 0; rr < 4; ++rr) addv[rr] = ADD[b * 96 + obase + rr];
#pragma unroll
            for (int n = 0; n < 6; ++n) {
                int tl = 2 * (rowbase + 16 * n) + phase;
                int tgl = t0 + tl;
#pragma unroll
                for (int rr = 0; rr < 4; ++rr) {
                    float v = acc[m][n][rr] + addv[rr];
                    if (tgl < 7)                  v -= CF[(b * 7 + tgl) * 96 + obase + rr];
                    if (tgl >= T2 - 7 && tgl < T2) v -= CB[(b * 7 + tgl - (T2 - 7)) * 96 + obase + rr];
                    L1[(og4 + rr) * 388 + tl] = v;
                }
            }
            __syncthreads();
            // dword-coalesced store: 16 rows x 384 f32
            for (int g = tid; g < 6144; g += 256) {
                int row = g / 384, col = g % 384;
                int t = t0 + col;
                if (t < TO) {
                    int o_g = mh * 48 + m * 16 + row;
                    Fout[((size_t)(b * 96 + o_g)) * TO + t] = L1[row * 388 + col];
                }
            }
            __syncthreads();   // protect L1 reuse by next chunk
        }
    }
}

extern "C" void kernel_launch(void* const* d_in, const int* in_sizes, int n_in,
                              void* d_out, int out_size, void* d_ws, size_t ws_size,
                              hipStream_t stream)
{
    const float* x       = (const float*)d_in[0];
    const float* offset0 = (const float*)d_in[1];
    const float* offset1 = (const float*)d_in[2];
    const float* conv_w0 = (const float*)d_in[5];
    const float* conv_b0 = (const float*)d_in[6];
    const float* conv_w1 = (const float*)d_in[7];
    const float* conv_b1 = (const float*)d_in[8];
    const float* off_w0  = (const float*)d_in[9];
    const float* off_b0  = (const float*)d_in[10];
    const float* off_w1  = (const float*)d_in[11];
    const float* off_b1  = (const float*)d_in[12];
    const float* cmask0  = (const float*)d_in[13];
    const float* cmask1  = (const float*)d_in[14];
    const float* omask0  = (const float*)d_in[15];
    const float* omask1  = (const float*)d_in[16];

    char* ws = (char*)d_ws;
    float*    Wplain = (float*)(ws);                  // 1,105,920
    ushort_t* Wp0    = (ushort_t*)(ws + 1105920);     // 331,776
    ushort_t* Wp1    = (ushort_t*)(ws + 1437696);     // 331,776
    float*    ADD0   = (float*)(ws + 1769472);        // 24,576
    float*    ADD1   = (float*)(ws + 1794048);        // 24,576
    float*    CF0    = (float*)(ws + 1818624);        // 172,032
    float*    CB0    = (float*)(ws + 1990656);        // 172,032
    float*    CF1    = (float*)(ws + 2162688);        // 172,032
    float*    CB1    = (float*)(ws + 2334720);        // 172,032
    ushort_t* H1     = (ushort_t*)(ws + 2506752);     // 25,165,824
    float* out = (float*)d_out;

    prepA<<<1128, 256, 0, stream>>>(conv_w0, cmask0, conv_w1, cmask1,
                                    off_w0, off_b0, omask0, conv_b0, offset0,
                                    off_w1, off_b1, omask1, conv_b1, offset1,
                                    Wplain, ADD0, ADD1);
    prepB<<<1320, 256, 0, stream>>>(Wplain, x, Wp0, Wp1, CF0, CB0);

    (void)hipFuncSetAttribute(reinterpret_cast<const void*>(&conv_poly<0>),
                              hipFuncAttributeMaxDynamicSharedMemorySize, LDS_TOTAL);
    (void)hipFuncSetAttribute(reinterpret_cast<const void*>(&conv_poly<1>),
                              hipFuncAttributeMaxDynamicSharedMemorySize, LDS_TOTAL);

    conv_poly<0><<<dim3(6, 64, 2), 256, LDS_TOTAL, stream>>>(x, nullptr, Wp0, ADD0, CF0, CB0,
                                                             H1, nullptr, 1024);
    prep_bnd1<<<96, 64, 0, stream>>>(Wplain + 138240, H1, CF1, CB1);
    conv_poly<1><<<dim3(11, 64, 2), 256, LDS_TOTAL, stream>>>(nullptr, H1, Wp1, ADD1, CF1, CB1,
                                                              nullptr, out, 2048);
}

// Round 5
// 202.328 us; speedup vs baseline: 1.2145x; 1.0702x over previous
//
#include <hip/hip_runtime.h>

typedef unsigned short ushort_t;
typedef unsigned int u32;
typedef short bf16x8 __attribute__((ext_vector_type(8)));
typedef float f32x4 __attribute__((ext_vector_type(4)));
typedef u32 u32x4 __attribute__((ext_vector_type(4)));

__device__ __forceinline__ float bf2f(ushort_t u) {
    u32 x = ((u32)u) << 16; float f; __builtin_memcpy(&f, &x, 4); return f;
}
__device__ __forceinline__ ushort_t f2bf(float f) {
    u32 x; __builtin_memcpy(&x, &f, 4);
    x = x + 0x7fffu + ((x >> 16) & 1u);
    return (ushort_t)(x >> 16);
}

#define NBB 192                       /* base rows per block */
#define UROWS 200                     /* NBB + 8 halo */
#define USTRB 208                     /* bytes per U row (96 bf16 + pad) */
#define UB_BYTES (UROWS * USTRB)      /* 41600 */
#define LDS_TOTAL UB_BYTES            /* U tile only; epilogue reuses it */
#define LSTR1 389                     /* stage1 epilogue f32 row stride (coprime 32) */

// ---------- prepA: fold unpool+mask -> Wplain [st][cc][k][o]  +  ADD tables ----
__global__ void prepA(const float* __restrict__ w0, const float* __restrict__ m0,
                      const float* __restrict__ w1, const float* __restrict__ m1,
                      const float* __restrict__ offw0, const float* __restrict__ offb0,
                      const float* __restrict__ omask0, const float* __restrict__ convb0,
                      const float* __restrict__ off0,
                      const float* __restrict__ offw1, const float* __restrict__ offb1,
                      const float* __restrict__ omask1, const float* __restrict__ convb1,
                      const float* __restrict__ off1,
                      float* __restrict__ Wplain, float* __restrict__ ADD0,
                      float* __restrict__ ADD1)
{
    int idx = blockIdx.x * 256 + threadIdx.x;
    if (idx < 276480) {                       // o fastest -> coalesced writes
        int o = idx % 96;
        int k = (idx / 96) % 15;
        int cc = (idx / 1440) % 96;
        int st = idx / 138240;
        const float* w = st ? w1 : w0;
        const float* mk = st ? m1 : m0;
        int cpj = st ? 8 : 16;
        int i = cc / cpj, c = cc % cpj;
        float s = 0.f;
#pragma unroll
        for (int d = 0; d < 2; ++d) {
            int f = (2 * i + d) * cpj + c;
            s += w[(o * 192 + f) * 15 + k] * mk[(o * 192 + f) * 15 + k];
        }
        Wplain[st * 138240 + (cc * 15 + k) * 96 + o] = s;
    } else if (idx < 276480 + 12288) {
        int a = idx - 276480;
        int st = a / 6144; int a2 = a % 6144;
        int o = a2 % 96, b = a2 / 96;
        const float* ow = st ? offw1 : offw0;
        const float* ob = st ? offb1 : offb0;
        const float* om = st ? omask1 : omask0;
        const float* cb = st ? convb1 : convb0;
        const float* of = st ? off1 : off0;
        int J = st ? 72 : 36;
        float s = 0.f;
        for (int j2 = 0; j2 < J; ++j2) s += ow[o * J + j2] * om[o * J + j2] * of[b * J + j2];
        (st ? ADD1 : ADD0)[b * 96 + o] = cb[o] + (s + ob[o]) * 0.01f;
    }
}

// ---------- boundary-correction helper (Wplain layout [cc][k][o]) ----------
template<int BF16SRC>
__device__ __forceinline__ void bnd_compute(const float* __restrict__ WP,
                                            const float* __restrict__ srcF,
                                            const ushort_t* __restrict__ srcB,
                                            float* __restrict__ CF, float* __restrict__ CB,
                                            int T, int b, int o)
{
    float Ga[15], Gb[15];
#pragma unroll
    for (int k = 0; k < 15; ++k) { Ga[k] = 0.f; Gb[k] = 0.f; }
    for (int cc = 0; cc < 96; ++cc) {
        float x0, x1;
        if (BF16SRC) {
            x0 = bf2f(srcB[(size_t)b * T * 96 + cc]);
            x1 = bf2f(srcB[((size_t)b * T + (T - 1)) * 96 + cc]);
        } else {
            x0 = bf2f(f2bf(srcF[(size_t)b * T * 96 + cc]));
            x1 = bf2f(f2bf(srcF[((size_t)b * T + (T - 1)) * 96 + cc]));
        }
        const float* wb2 = WP + cc * 15 * 96 + o;
#pragma unroll
        for (int k = 0; k < 15; ++k) {
            float w = wb2[k * 96];
            Ga[k] += w * x0; Gb[k] += w * x1;
        }
    }
#pragma unroll
    for (int t = 0; t < 7; ++t) {
        float s0 = 0.f, s1 = 0.f;
#pragma unroll
        for (int k = 0; k < 15; ++k) { if (k <= 6 - t) s0 += Ga[k]; if (k >= 14 - t) s1 += Gb[k]; }
        CF[(b * 7 + t) * 96 + o] = s0;
        CB[(b * 7 + t) * 96 + o] = s1;
    }
}

// ---------- prepB: polyphase A-frag weights (direct-load layout) + stage0 bnd --
// Wp: [((j*2+mh)*2+p)*9 + cb*3 + m]*512 + lane*8 + e   (1 KB contiguous per frag)
__global__ void prepB(const float* __restrict__ Wplain, const float* __restrict__ x,
                      ushort_t* __restrict__ Wp0, ushort_t* __restrict__ Wp1,
                      float* __restrict__ CF0, float* __restrict__ CB0)
{
    int idx = blockIdx.x * 256 + threadIdx.x;
    if (idx < 331776) {                       // 2st x 2p x 9j x 96o x 96cc
        int cc = idx % 96; int t = idx / 96;
        int o = t % 96; t /= 96;
        int j = t % 9; t /= 9;
        int p = t % 2; int st = t / 2;
        const float* WP = Wplain + (size_t)st * 138240;
        int kk[4]; float cf[4];
        if (p == 0) { kk[0]=2*j;   cf[0]=0.75f; kk[1]=2*j-2; cf[1]=0.25f;
                      kk[2]=2*j+1; cf[2]=0.25f; kk[3]=2*j-1; cf[3]=0.75f; }
        else        { kk[0]=2*j;   cf[0]=0.25f; kk[1]=2*j-2; cf[1]=0.75f;
                      kk[2]=2*j-1; cf[2]=0.75f; kk[3]=2*j-3; cf[3]=0.25f; }
        float s = 0.f;
#pragma unroll
        for (int q = 0; q < 4; ++q) {
            int k = kk[q];
            if (k >= 0 && k < 15) s += cf[q] * WP[(cc * 15 + k) * 96 + o];
        }
        int lane = (o & 15) | (((cc >> 3) & 3) << 4);
        int mh = (o >> 4) / 3, m = (o >> 4) % 3;
        int pos = ((((j * 2 + mh) * 2 + p) * 9) + (cc >> 5) * 3 + m) * 512 + lane * 8 + (cc & 7);
        (st ? Wp1 : Wp0)[pos] = f2bf(s);
    } else if (idx < 331776 + 6144) {
        int a = idx - 331776;
        int o = a % 96, b = a / 96;
        bnd_compute<0>(Wplain, x, nullptr, CF0, CB0, 1024, b, o);
    }
}

__global__ void prep_bnd1(const float* __restrict__ WP, const ushort_t* __restrict__ H1,
                          float* __restrict__ CF, float* __restrict__ CB)
{
    int idx = blockIdx.x * 64 + threadIdx.x;
    if (idx >= 6144) return;
    int o = idx % 96, b = idx / 96;
    bnd_compute<1>(WP, nullptr, H1, CF, CB, 2048, b, o);
}

// ---------- fused polyphase conv; weights global->reg, barrier-free tap loop ---
template<int STAGE>
__launch_bounds__(256, 2)
__global__ void conv_poly(const float* __restrict__ Xf, const ushort_t* __restrict__ Hbf,
                          const ushort_t* __restrict__ Wp, const float* __restrict__ ADD,
                          const float* __restrict__ CF, const float* __restrict__ CB,
                          ushort_t* __restrict__ Hout, float* __restrict__ Fout, int T)
{
    extern __shared__ char smem[];
    char* Ub = smem;

    const int tid = threadIdx.x;
    const int lane = tid & 63;
    const int wid = tid >> 6;         // 0..3
    const int b = blockIdx.y;
    const int tg = blockIdx.x;
    const int mh = blockIdx.z;        // output-channel half (0: o<48, 1: o>=48)
    const int phase = wid & 1;
    const int nq = wid >> 1;          // 0..1, 96 base rows each
    const int rb0 = tg * NBB - 4;

    // per-wave A-frag base: group index ((j*2+mh)*2+phase), 4608 ushorts apart
    const ushort_t* wgl = Wp + (size_t)(mh * 2 + phase) * 4608 + lane * 8;

    // prefetch tap 0 A-frags into registers (overlaps U staging below)
    bf16x8 acur[9], anxt[9];
#pragma unroll
    for (int q = 0; q < 9; ++q)
        acur[q] = *(const bf16x8*)(wgl + q * 512);

    // stage U at base rate, clamped rows, (r&8)<<1 XOR swizzle on 16B granules
    if (STAGE == 0) {
        const float* xb = Xf + (size_t)b * T * 96;
        for (int idx = tid; idx < UROWS * 12; idx += 256) {
            int r = idx / 12, q = idx - r * 12;
            int rg = rb0 + r; rg = rg < 0 ? 0 : (rg > T - 1 ? T - 1 : rg);
            const float* src = xb + (size_t)rg * 96 + q * 8;
            float4 a = *(const float4*)src;
            float4 c2 = *(const float4*)(src + 4);
            u32x4 v;
            v[0] = (u32)f2bf(a.x) | ((u32)f2bf(a.y) << 16);
            v[1] = (u32)f2bf(a.z) | ((u32)f2bf(a.w) << 16);
            v[2] = (u32)f2bf(c2.x) | ((u32)f2bf(c2.y) << 16);
            v[3] = (u32)f2bf(c2.z) | ((u32)f2bf(c2.w) << 16);
            int off = r * USTRB + q * 16; off ^= (r & 8) << 1;
            *(u32x4*)(Ub + off) = v;
        }
    } else {
        const ushort_t* xb = Hbf + (size_t)b * T * 96;
        for (int idx = tid; idx < UROWS * 12; idx += 256) {
            int r = idx / 12, q = idx - r * 12;
            int rg = rb0 + r; rg = rg < 0 ? 0 : (rg > T - 1 ? T - 1 : rg);
            u32x4 v = *(const u32x4*)(xb + (size_t)rg * 96 + q * 8);
            int off = r * USTRB + q * 16; off ^= (r & 8) << 1;
            *(u32x4*)(Ub + off) = v;
        }
    }
    __syncthreads();   // U visible to all waves

    f32x4 acc[3][6];
#pragma unroll
    for (int m = 0; m < 3; ++m)
#pragma unroll
        for (int n = 0; n < 6; ++n) acc[m][n] = (f32x4){0.f, 0.f, 0.f, 0.f};

    const int rowbase = 96 * nq + (lane & 15);
    const int og16 = (lane >> 4) * 16;

#pragma unroll
    for (int j = 0; j < 9; ++j) {
        if (j < 8) {   // prefetch next tap's 9 A-frags (L2-hot)
#pragma unroll
            for (int q = 0; q < 9; ++q)
                anxt[q] = *(const bf16x8*)(wgl + (size_t)(j + 1) * 18432 + q * 512);
        }
#pragma unroll
        for (int cb = 0; cb < 3; ++cb) {
            bf16x8 bfr[6];
#pragma unroll
            for (int n = 0; n < 6; ++n) {
                int row = rowbase + n * 16 + j;
                int off = row * USTRB + cb * 64 + og16; off ^= (row & 8) << 1;
                bfr[n] = *(const bf16x8*)(Ub + off);
            }
            __builtin_amdgcn_s_setprio(1);
#pragma unroll
            for (int m = 0; m < 3; ++m)
#pragma unroll
                for (int n = 0; n < 6; ++n)
                    acc[m][n] = __builtin_amdgcn_mfma_f32_16x16x32_bf16(acur[cb * 3 + m], bfr[n], acc[m][n], 0, 0, 0);
            __builtin_amdgcn_s_setprio(0);
        }
        if (j < 8) {
#pragma unroll
            for (int q = 0; q < 9; ++q) acur[q] = anxt[q];
        }
        __builtin_amdgcn_sched_barrier(0);   // pin pipeline depth to 1 tap
    }

    // ---------------- epilogue: LDS transpose -> coalesced stores --------------
    const int T2 = 2 * T;
    const int t0 = tg * 2 * NBB;          // block's output t-range base (384 wide)
    const int og4 = (lane >> 4) * 4;

    __syncthreads();   // all B-frag reads done before Ub reuse

    if (STAGE == 0) {
        // deposit all 48 ch x 384 t as bf16 rows [t][48ch] (stride 104 B)
        ushort_t* L0 = (ushort_t*)Ub;
#pragma unroll
        for (int m = 0; m < 3; ++m) {
            int obase = mh * 48 + m * 16 + og4;
            float addv[4];
#pragma unroll
            for (int rr = 0; rr < 4; ++rr) addv[rr] = ADD[b * 96 + obase + rr];
#pragma unroll
            for (int n = 0; n < 6; ++n) {
                int tl = 2 * (rowbase + 16 * n) + phase;   // 0..383
                int tgl = t0 + tl;
                ushort_t pk[4];
#pragma unroll
                for (int rr = 0; rr < 4; ++rr) {
                    float v = acc[m][n][rr] + addv[rr];
                    if (tgl < 7)                   v -= CF[(b * 7 + tgl) * 96 + obase + rr];
                    if (tgl >= T2 - 7 && tgl < T2) v -= CB[(b * 7 + tgl - (T2 - 7)) * 96 + obase + rr];
                    v = v > 0.f ? v : 0.2f * v;
                    pk[rr] = f2bf(v);
                }
                uint2 w2;
                w2.x = (u32)pk[0] | ((u32)pk[1] << 16);
                w2.y = (u32)pk[2] | ((u32)pk[3] << 16);
                *(uint2*)((char*)L0 + tl * 104 + (m * 16 + og4) * 2) = w2;
            }
        }
        __syncthreads();
        // store contiguous 96B half-rows of H1 [b][t][96]
        for (int g = tid; g < 384 * 6; g += 256) {
            int row = g / 6, col = g % 6;
            int t = t0 + row;
            if (t < T2) {
                u32x4 v = *(const u32x4*)((char*)L0 + row * 104 + col * 16);
                *(u32x4*)((char*)Hout + ((size_t)(b * T2 + t) * 96 + mh * 48) * 2 + col * 16) = v;
            }
        }
    } else {
        const int TO = T2 - 1;   // 4095
        float* L1 = (float*)Ub;  // per-chunk [16 o][LSTR1 f32]
#pragma unroll
        for (int m = 0; m < 3; ++m) {
            int obase = mh * 48 + m * 16 + og4;
            float addv[4];
#pragma unroll
            for (int rr = 0; rr < 4; ++rr) addv[rr] = ADD[b * 96 + obase + rr];
#pragma unroll
            for (int n = 0; n < 6; ++n) {
                int tl = 2 * (rowbase + 16 * n) + phase;
                int tgl = t0 + tl;
#pragma unroll
                for (int rr = 0; rr < 4; ++rr) {
                    float v = acc[m][n][rr] + addv[rr];
                    if (tgl < 7)                   v -= CF[(b * 7 + tgl) * 96 + obase + rr];
                    if (tgl >= T2 - 7 && tgl < T2) v -= CB[(b * 7 + tgl - (T2 - 7)) * 96 + obase + rr];
                    L1[(og4 + rr) * LSTR1 + tl] = v;
                }
            }
            __syncthreads();
            // dword-coalesced store: 16 rows x 384 f32
            for (int g = tid; g < 6144; g += 256) {
                int row = g / 384, col = g % 384;
                int t = t0 + col;
                if (t < TO) {
                    int o_g = mh * 48 + m * 16 + row;
                    Fout[((size_t)(b * 96 + o_g)) * TO + t] = L1[row * LSTR1 + col];
                }
            }
            __syncthreads();   // protect L1 reuse by next chunk
        }
    }
}

extern "C" void kernel_launch(void* const* d_in, const int* in_sizes, int n_in,
                              void* d_out, int out_size, void* d_ws, size_t ws_size,
                              hipStream_t stream)
{
    const float* x       = (const float*)d_in[0];
    const float* offset0 = (const float*)d_in[1];
    const float* offset1 = (const float*)d_in[2];
    const float* conv_w0 = (const float*)d_in[5];
    const float* conv_b0 = (const float*)d_in[6];
    const float* conv_w1 = (const float*)d_in[7];
    const float* conv_b1 = (const float*)d_in[8];
    const float* off_w0  = (const float*)d_in[9];
    const float* off_b0  = (const float*)d_in[10];
    const float* off_w1  = (const float*)d_in[11];
    const float* off_b1  = (const float*)d_in[12];
    const float* cmask0  = (const float*)d_in[13];
    const float* cmask1  = (const float*)d_in[14];
    const float* omask0  = (const float*)d_in[15];
    const float* omask1  = (const float*)d_in[16];

    char* ws = (char*)d_ws;
    float*    Wplain = (float*)(ws);                  // 1,105,920
    ushort_t* Wp0    = (ushort_t*)(ws + 1105920);     // 331,776
    ushort_t* Wp1    = (ushort_t*)(ws + 1437696);     // 331,776
    float*    ADD0   = (float*)(ws + 1769472);        // 24,576
    float*    ADD1   = (float*)(ws + 1794048);        // 24,576
    float*    CF0    = (float*)(ws + 1818624);        // 172,032
    float*    CB0    = (float*)(ws + 1990656);        // 172,032
    float*    CF1    = (float*)(ws + 2162688);        // 172,032
    float*    CB1    = (float*)(ws + 2334720);        // 172,032
    ushort_t* H1     = (ushort_t*)(ws + 2506752);     // 25,165,824
    float* out = (float*)d_out;

    prepA<<<1128, 256, 0, stream>>>(conv_w0, cmask0, conv_w1, cmask1,
                                    off_w0, off_b0, omask0, conv_b0, offset0,
                                    off_w1, off_b1, omask1, conv_b1, offset1,
                                    Wplain, ADD0, ADD1);
    prepB<<<1320, 256, 0, stream>>>(Wplain, x, Wp0, Wp1, CF0, CB0);

    (void)hipFuncSetAttribute(reinterpret_cast<const void*>(&conv_poly<0>),
                              hipFuncAttributeMaxDynamicSharedMemorySize, LDS_TOTAL);
    (void)hipFuncSetAttribute(reinterpret_cast<const void*>(&conv_poly<1>),
                              hipFuncAttributeMaxDynamicSharedMemorySize, LDS_TOTAL);

    conv_poly<0><<<dim3(6, 64, 2), 256, LDS_TOTAL, stream>>>(x, nullptr, Wp0, ADD0, CF0, CB0,
                                                             H1, nullptr, 1024);
    prep_bnd1<<<96, 64, 0, stream>>>(Wplain + 138240, H1, CF1, CB1);
    conv_poly<1><<<dim3(11, 64, 2), 256, LDS_TOTAL, stream>>>(nullptr, H1, Wp1, ADD1, CF1, CB1,
                                                              nullptr, out, 2048);
}

// Round 6
// 146.305 us; speedup vs baseline: 1.6796x; 1.3829x over previous
//
#include <hip/hip_runtime.h>

typedef unsigned short ushort_t;
typedef unsigned int u32;
typedef short bf16x8 __attribute__((ext_vector_type(8)));
typedef float f32x4 __attribute__((ext_vector_type(4)));
typedef u32 u32x4 __attribute__((ext_vector_type(4)));

__device__ __forceinline__ float bf2f(ushort_t u) {
    u32 x = ((u32)u) << 16; float f; __builtin_memcpy(&f, &x, 4); return f;
}
__device__ __forceinline__ ushort_t f2bf(float f) {
    u32 x; __builtin_memcpy(&x, &f, 4);
    x = x + 0x7fffu + ((x >> 16) & 1u);
    return (ushort_t)(x >> 16);
}

#define NBB 192                       /* base rows per block */
#define UROWS 200                     /* NBB + 8 halo */
#define USTRB 208                     /* bytes per U row (96 bf16 + pad) */
#define UB_BYTES (UROWS * USTRB)      /* 41600 */
#define LDS_TOTAL UB_BYTES
#define LSTR1 388                     /* stage1 epilogue f32 row stride */

// ---------- prepA: fold unpool+mask -> Wplain [st][cc][k][o]  +  ADD tables ----
__global__ void prepA(const float* __restrict__ w0, const float* __restrict__ m0,
                      const float* __restrict__ w1, const float* __restrict__ m1,
                      const float* __restrict__ offw0, const float* __restrict__ offb0,
                      const float* __restrict__ omask0, const float* __restrict__ convb0,
                      const float* __restrict__ off0,
                      const float* __restrict__ offw1, const float* __restrict__ offb1,
                      const float* __restrict__ omask1, const float* __restrict__ convb1,
                      const float* __restrict__ off1,
                      float* __restrict__ Wplain, float* __restrict__ ADD0,
                      float* __restrict__ ADD1)
{
    int idx = blockIdx.x * 256 + threadIdx.x;
    if (idx < 276480) {                       // o fastest -> coalesced writes
        int o = idx % 96;
        int k = (idx / 96) % 15;
        int cc = (idx / 1440) % 96;
        int st = idx / 138240;
        const float* w = st ? w1 : w0;
        const float* mk = st ? m1 : m0;
        int cpj = st ? 8 : 16;
        int i = cc / cpj, c = cc % cpj;
        float s = 0.f;
#pragma unroll
        for (int d = 0; d < 2; ++d) {
            int f = (2 * i + d) * cpj + c;
            s += w[(o * 192 + f) * 15 + k] * mk[(o * 192 + f) * 15 + k];
        }
        Wplain[st * 138240 + (cc * 15 + k) * 96 + o] = s;
    } else if (idx < 276480 + 12288) {
        int a = idx - 276480;
        int st = a / 6144; int a2 = a % 6144;
        int o = a2 % 96, b = a2 / 96;
        const float* ow = st ? offw1 : offw0;
        const float* ob = st ? offb1 : offb0;
        const float* om = st ? omask1 : omask0;
        const float* cb = st ? convb1 : convb0;
        const float* of = st ? off1 : off0;
        int J = st ? 72 : 36;
        float s = 0.f;
        for (int j2 = 0; j2 < J; ++j2) s += ow[o * J + j2] * om[o * J + j2] * of[b * J + j2];
        (st ? ADD1 : ADD0)[b * 96 + o] = cb[o] + (s + ob[o]) * 0.01f;
    }
}

// ---------- prepB: polyphase A-frag weights (direct-load layout) ---------------
// Wp: [((j*2+mh)*2+p)*9 + cb*3 + m]*512 + lane*8 + e   (1 KB contiguous per frag)
__global__ void prepB(const float* __restrict__ Wplain,
                      ushort_t* __restrict__ Wp0, ushort_t* __restrict__ Wp1)
{
    int idx = blockIdx.x * 256 + threadIdx.x;
    if (idx >= 331776) return;                // 2st x 2p x 9j x 96o x 96cc
    int cc = idx % 96; int t = idx / 96;
    int o = t % 96; t /= 96;
    int j = t % 9; t /= 9;
    int p = t % 2; int st = t / 2;
    const float* WP = Wplain + (size_t)st * 138240;
    int kk[4]; float cf[4];
    if (p == 0) { kk[0]=2*j;   cf[0]=0.75f; kk[1]=2*j-2; cf[1]=0.25f;
                  kk[2]=2*j+1; cf[2]=0.25f; kk[3]=2*j-1; cf[3]=0.75f; }
    else        { kk[0]=2*j;   cf[0]=0.25f; kk[1]=2*j-2; cf[1]=0.75f;
                  kk[2]=2*j-1; cf[2]=0.75f; kk[3]=2*j-3; cf[3]=0.25f; }
    float s = 0.f;
#pragma unroll
    for (int q = 0; q < 4; ++q) {
        int k = kk[q];
        if (k >= 0 && k < 15) s += cf[q] * WP[(cc * 15 + k) * 96 + o];
    }
    int lane = (o & 15) | (((cc >> 3) & 3) << 4);
    int mh = (o >> 4) / 3, m = (o >> 4) % 3;
    int pos = ((((j * 2 + mh) * 2 + p) * 9) + (cc >> 5) * 3 + m) * 512 + lane * 8 + (cc & 7);
    (st ? Wp1 : Wp0)[pos] = f2bf(s);
}

// ---------- prep_G: wide boundary dot-products, lane = o (coalesced) ----------
template<int BF16SRC>
__global__ void prep_G(const float* __restrict__ WP, const float* __restrict__ srcF,
                       const ushort_t* __restrict__ srcB, float* __restrict__ G, int T)
{
    int idx = blockIdx.x * 256 + threadIdx.x;
    if (idx >= 184320) return;                // 64b x 2side x 15k x 96o
    int o = idx % 96; int t = idx / 96;
    int k = t % 15; t /= 15;
    int side = t % 2; int b = t / 2;
    const float* wbase = WP + k * 96 + o;     // + cc*1440, lane-coalesced over o
    int row = side ? T - 1 : 0;
    float s = 0.f;
    if (BF16SRC) {
        const ushort_t* xr = srcB + ((size_t)b * T + row) * 96;
        for (int cc = 0; cc < 96; ++cc)
            s += wbase[cc * 1440] * bf2f(xr[cc]);
    } else {
        const float* xr = srcF + ((size_t)b * T + row) * 96;
        for (int cc = 0; cc < 96; ++cc)
            s += wbase[cc * 1440] * bf2f(f2bf(xr[cc]));
    }
    G[((size_t)(b * 96 + o) * 15 + k) * 2 + side] = s;
}

// ---------- prep_cfb: prefix sums of G -> CF/CB ----------
__global__ void prep_cfb(const float* __restrict__ G, float* __restrict__ CF,
                         float* __restrict__ CB)
{
    int idx = blockIdx.x * 256 + threadIdx.x;
    if (idx >= 86016) return;                 // 64 x 96 x 14
    int seg = idx % 14; int r = idx / 14;
    int o = r % 96; int b = r / 96;
    bool front = seg < 7; int t = front ? seg : seg - 7;
    float s = 0.f;
    if (front) { for (int k = 0; k <= 6 - t; ++k)   s += G[(((size_t)(b*96+o)*15)+k)*2 + 0]; }
    else       { for (int k = 14 - t; k <= 14; ++k) s += G[(((size_t)(b*96+o)*15)+k)*2 + 1]; }
    (front ? CF : CB)[(b * 7 + t) * 96 + o] = s;
}

// ---------- fused polyphase conv; free-running taps, 3 blocks/CU --------------
template<int STAGE>
__launch_bounds__(256, 3)
__global__ void conv_poly(const float* __restrict__ Xf, const ushort_t* __restrict__ Hbf,
                          const ushort_t* __restrict__ Wp, const float* __restrict__ ADD,
                          const float* __restrict__ CF, const float* __restrict__ CB,
                          ushort_t* __restrict__ Hout, float* __restrict__ Fout, int T)
{
    extern __shared__ char smem[];
    char* Ub = smem;

    const int tid = threadIdx.x;
    const int lane = tid & 63;
    const int wid = tid >> 6;         // 0..3
    const int b = blockIdx.y;
    const int tg = blockIdx.x;
    const int mh = blockIdx.z;        // output-channel half
    const int phase = wid & 1;
    const int nq = wid >> 1;          // 0..1, 96 base rows each
    const int rb0 = tg * NBB - 4;

    const ushort_t* wgl = Wp + (size_t)(mh * 2 + phase) * 4608 + lane * 8;

    // stage U at base rate, clamped rows, (r&8)<<1 XOR swizzle on 16B granules
    if (STAGE == 0) {
        const float* xb = Xf + (size_t)b * T * 96;
        for (int idx = tid; idx < UROWS * 12; idx += 256) {
            int r = idx / 12, q = idx - r * 12;
            int rg = rb0 + r; rg = rg < 0 ? 0 : (rg > T - 1 ? T - 1 : rg);
            const float* src = xb + (size_t)rg * 96 + q * 8;
            float4 a = *(const float4*)src;
            float4 c2 = *(const float4*)(src + 4);
            u32x4 v;
            v[0] = (u32)f2bf(a.x) | ((u32)f2bf(a.y) << 16);
            v[1] = (u32)f2bf(a.z) | ((u32)f2bf(a.w) << 16);
            v[2] = (u32)f2bf(c2.x) | ((u32)f2bf(c2.y) << 16);
            v[3] = (u32)f2bf(c2.z) | ((u32)f2bf(c2.w) << 16);
            int off = (r * USTRB + q * 16) ^ ((r & 8) << 1);
            *(u32x4*)(Ub + off) = v;
        }
    } else {
        const ushort_t* xb = Hbf + (size_t)b * T * 96;
        for (int idx = tid; idx < UROWS * 12; idx += 256) {
            int r = idx / 12, q = idx - r * 12;
            int rg = rb0 + r; rg = rg < 0 ? 0 : (rg > T - 1 ? T - 1 : rg);
            u32x4 v = *(const u32x4*)(xb + (size_t)rg * 96 + q * 8);
            int off = (r * USTRB + q * 16) ^ ((r & 8) << 1);
            *(u32x4*)(Ub + off) = v;
        }
    }
    __syncthreads();   // U visible to all waves

    f32x4 acc[3][6];
#pragma unroll
    for (int m = 0; m < 3; ++m)
#pragma unroll
        for (int n = 0; n < 6; ++n) acc[m][n] = (f32x4){0.f, 0.f, 0.f, 0.f};

    const int rowbase = 96 * nq + (lane & 15);
    const int og16 = (lane >> 4) * 16;

#pragma unroll
    for (int j = 0; j < 9; ++j) {
        // tap j A-frags (global, L2-hot) — plain loads, compiler hoists/pipelines
        const ushort_t* wj = wgl + (size_t)j * 18432;
        bf16x8 aj[9];
#pragma unroll
        for (int q = 0; q < 9; ++q)
            aj[q] = *(const bf16x8*)(wj + q * 512);

        const int rj = rowbase + j;
        const int bj = rj * USTRB;
        const int X = (rj & 8) << 1;
#pragma unroll
        for (int cb = 0; cb < 3; ++cb) {
            const int off0 = (bj + cb * 64 + og16) ^ X;   // XOR commutes with +n*3328
            bf16x8 bfr[6];
#pragma unroll
            for (int n = 0; n < 6; ++n)
                bfr[n] = *(const bf16x8*)(Ub + off0 + n * 3328);
#pragma unroll
            for (int m = 0; m < 3; ++m)
#pragma unroll
                for (int n = 0; n < 6; ++n)
                    acc[m][n] = __builtin_amdgcn_mfma_f32_16x16x32_bf16(aj[cb * 3 + m], bfr[n], acc[m][n], 0, 0, 0);
        }
    }

    // ---------------- epilogue: LDS transpose -> coalesced stores --------------
    const int T2 = 2 * T;
    const int t0 = tg * 2 * NBB;
    const int og4 = (lane >> 4) * 4;

    __syncthreads();   // all B-frag reads done before Ub reuse

    if (STAGE == 0) {
        ushort_t* L0 = (ushort_t*)Ub;   // [384 t][48 ch] bf16, stride 104 B
#pragma unroll
        for (int m = 0; m < 3; ++m) {
            int obase = mh * 48 + m * 16 + og4;
            float addv[4];
#pragma unroll
            for (int rr = 0; rr < 4; ++rr) addv[rr] = ADD[b * 96 + obase + rr];
#pragma unroll
            for (int n = 0; n < 6; ++n) {
                int tl = 2 * (rowbase + 16 * n) + phase;   // 0..383
                int tgl = t0 + tl;
                ushort_t pk[4];
#pragma unroll
                for (int rr = 0; rr < 4; ++rr) {
                    float v = acc[m][n][rr] + addv[rr];
                    if (tgl < 7)                   v -= CF[(b * 7 + tgl) * 96 + obase + rr];
                    if (tgl >= T2 - 7 && tgl < T2) v -= CB[(b * 7 + tgl - (T2 - 7)) * 96 + obase + rr];
                    v = v > 0.f ? v : 0.2f * v;
                    pk[rr] = f2bf(v);
                }
                uint2 w2;
                w2.x = (u32)pk[0] | ((u32)pk[1] << 16);
                w2.y = (u32)pk[2] | ((u32)pk[3] << 16);
                *(uint2*)((char*)L0 + tl * 104 + (m * 16 + og4) * 2) = w2;
            }
        }
        __syncthreads();
        for (int g = tid; g < 384 * 6; g += 256) {
            int row = g / 6, col = g % 6;
            int t = t0 + row;
            if (t < T2) {
                u32x4 v = *(const u32x4*)((char*)L0 + row * 104 + col * 16);
                *(u32x4*)((char*)Hout + ((size_t)(b * T2 + t) * 96 + mh * 48) * 2 + col * 16) = v;
            }
        }
    } else {
        const int TO = T2 - 1;   // 4095
        float* L1 = (float*)Ub;  // per-chunk [16 o][LSTR1 f32], (row&3) stagger
#pragma unroll
        for (int m = 0; m < 3; ++m) {
            int obase = mh * 48 + m * 16 + og4;
            float addv[4];
#pragma unroll
            for (int rr = 0; rr < 4; ++rr) addv[rr] = ADD[b * 96 + obase + rr];
#pragma unroll
            for (int n = 0; n < 6; ++n) {
                int tl = 2 * (rowbase + 16 * n) + phase;
                int tgl = t0 + tl;
#pragma unroll
                for (int rr = 0; rr < 4; ++rr) {
                    float v = acc[m][n][rr] + addv[rr];
                    if (tgl < 7)                   v -= CF[(b * 7 + tgl) * 96 + obase + rr];
                    if (tgl >= T2 - 7 && tgl < T2) v -= CB[(b * 7 + tgl - (T2 - 7)) * 96 + obase + rr];
                    int rloc = og4 + rr;
                    L1[rloc * LSTR1 + tl + (rloc & 3)] = v;
                }
            }
            __syncthreads();
            for (int g = tid; g < 6144; g += 256) {
                int row = g / 384, col = g % 384;
                int t = t0 + col;
                if (t < TO) {
                    int o_g = mh * 48 + m * 16 + row;
                    Fout[((size_t)(b * 96 + o_g)) * TO + t] = L1[row * LSTR1 + col + (row & 3)];
                }
            }
            __syncthreads();
        }
    }
}

extern "C" void kernel_launch(void* const* d_in, const int* in_sizes, int n_in,
                              void* d_out, int out_size, void* d_ws, size_t ws_size,
                              hipStream_t stream)
{
    const float* x       = (const float*)d_in[0];
    const float* offset0 = (const float*)d_in[1];
    const float* offset1 = (const float*)d_in[2];
    const float* conv_w0 = (const float*)d_in[5];
    const float* conv_b0 = (const float*)d_in[6];
    const float* conv_w1 = (const float*)d_in[7];
    const float* conv_b1 = (const float*)d_in[8];
    const float* off_w0  = (const float*)d_in[9];
    const float* off_b0  = (const float*)d_in[10];
    const float* off_w1  = (const float*)d_in[11];
    const float* off_b1  = (const float*)d_in[12];
    const float* cmask0  = (const float*)d_in[13];
    const float* cmask1  = (const float*)d_in[14];
    const float* omask0  = (const float*)d_in[15];
    const float* omask1  = (const float*)d_in[16];

    char* ws = (char*)d_ws;
    float*    Wplain = (float*)(ws);                  // 1,105,920
    ushort_t* Wp0    = (ushort_t*)(ws + 1105920);     // 331,776
    ushort_t* Wp1    = (ushort_t*)(ws + 1437696);     // 331,776
    float*    ADD0   = (float*)(ws + 1769472);        // 24,576
    float*    ADD1   = (float*)(ws + 1794048);        // 24,576
    float*    CF0    = (float*)(ws + 1818624);        // 172,032
    float*    CB0    = (float*)(ws + 1990656);        // 172,032
    float*    CF1    = (float*)(ws + 2162688);        // 172,032
    float*    CB1    = (float*)(ws + 2334720);        // 172,032
    float*    G0     = (float*)(ws + 2506752);        // 737,280
    float*    G1     = (float*)(ws + 3244032);        // 737,280
    ushort_t* H1     = (ushort_t*)(ws + 3981312);     // 25,165,824
    float* out = (float*)d_out;

    prepA<<<1128, 256, 0, stream>>>(conv_w0, cmask0, conv_w1, cmask1,
                                    off_w0, off_b0, omask0, conv_b0, offset0,
                                    off_w1, off_b1, omask1, conv_b1, offset1,
                                    Wplain, ADD0, ADD1);
    prepB<<<1296, 256, 0, stream>>>(Wplain, Wp0, Wp1);
    prep_G<0><<<720, 256, 0, stream>>>(Wplain, x, nullptr, G0, 1024);
    prep_cfb<<<336, 256, 0, stream>>>(G0, CF0, CB0);

    (void)hipFuncSetAttribute(reinterpret_cast<const void*>(&conv_poly<0>),
                              hipFuncAttributeMaxDynamicSharedMemorySize, LDS_TOTAL);
    (void)hipFuncSetAttribute(reinterpret_cast<const void*>(&conv_poly<1>),
                              hipFuncAttributeMaxDynamicSharedMemorySize, LDS_TOTAL);

    conv_poly<0><<<dim3(6, 64, 2), 256, LDS_TOTAL, stream>>>(x, nullptr, Wp0, ADD0, CF0, CB0,
                                                             H1, nullptr, 1024);
    prep_G<1><<<720, 256, 0, stream>>>(Wplain + 138240, nullptr, H1, G1, 2048);
    prep_cfb<<<336, 256, 0, stream>>>(G1, CF1, CB1);
    conv_poly<1><<<dim3(11, 64, 2), 256, LDS_TOTAL, stream>>>(nullptr, H1, Wp1, ADD1, CF1, CB1,
                                                              nullptr, out, 2048);
}